// Round 2
// baseline (1174.547 us; speedup 1.0000x reference)
//
#include <hip/hip_runtime.h>
#include <hip/hip_bf16.h>

// ---------------- problem constants ----------------
#define B_    4
#define S_    1024
#define HID   4096
#define H_    32
#define KVH_  8
#define D_    128
#define T_    (B_ * S_)        // 4096
#define QKVD  (H_ * D_ + 2 * KVH_ * D_)  // 6144
#define NSLOT 8192

typedef __attribute__((ext_vector_type(8))) short short8;   // 8 bf16 = 4 VGPRs
typedef __attribute__((ext_vector_type(4))) float f32x4;

__device__ __forceinline__ unsigned short f2b(float f) {
  union { __hip_bfloat16 h; unsigned short u; } c;
  c.h = __float2bfloat16(f);
  return c.u;
}

// async global->LDS 16B. LDS dest must be wave-uniform base + lane*16.
__device__ __forceinline__ void async16(const void* g, void* l) {
  __builtin_amdgcn_global_load_lds(
      (const __attribute__((address_space(1))) unsigned int*)g,
      (__attribute__((address_space(3))) unsigned int*)l,
      16, 0, 0);
}

// ---------------- fp32 -> bf16 convert ----------------
__global__ void conv_bf16(const float* __restrict__ src,
                          unsigned short* __restrict__ dst, int n4) {
  int i = blockIdx.x * 256 + threadIdx.x;
  if (i >= n4) return;
  float4 v = reinterpret_cast<const float4*>(src)[i];
  ushort4 o;
  o.x = f2b(v.x); o.y = f2b(v.y); o.z = f2b(v.z); o.w = f2b(v.w);
  reinterpret_cast<ushort4*>(dst)[i] = o;
}

// ---------------- GEMM: C(M,N) f32 = A(M,K)bf16 * B(N,K)bf16 ^T --------------
// m97 structure: 128x128 tile, BK=32, 4 waves in 2x2, 16x16x32 MFMA.
// LDS 16B-chunk XOR swizzle (chunk ^= (row>>1)&3): within a 16-lane quarter
// phase each quad's reads cover all 8 bank groups -> 2-way max (free, m136).
__global__ __launch_bounds__(256) void gemm_bt(
    const unsigned short* __restrict__ A, const unsigned short* __restrict__ Bm,
    float* __restrict__ C, int M, int N, int K) {
  __shared__ unsigned short As[128 * 32];  // [row][32] swizzled, 8KB
  __shared__ unsigned short Bs[128 * 32];
  const int tid  = threadIdx.x;
  const int lane = tid & 63;
  const int w    = tid >> 6;
  const int quad = lane >> 4;
  const int l16  = lane & 15;

  // supercolumn rasterization: groups of 8 N-tiles sweep all M-tiles
  {
  }
  const int p = blockIdx.x + gridDim.x * blockIdx.y;
  const int tpg = 8 * gridDim.y;          // tiles per supercolumn group
  const int g = p / tpg, rr = p % tpg;
  const int bm = (rr >> 3) * 128;
  const int bn = (g * 8 + (rr & 7)) * 128;

  const int wm = (w >> 1) * 64;
  const int wn = (w & 1) * 64;

  const int srow = tid >> 2;                               // 0..63
  const int scol = (((tid & 3) ^ ((tid >> 3) & 3)) * 8);   // swizzled src chunk
  const int qoff = (quad ^ ((l16 >> 1) & 3)) * 8;          // swizzled frag chunk
  const size_t a0 = (size_t)(bm + srow) * K + scol;
  const size_t a1 = (size_t)(bm + 64 + srow) * K + scol;
  const size_t b0 = (size_t)(bn + srow) * K + scol;
  const size_t b1 = (size_t)(bn + 64 + srow) * K + scol;

  f32x4 acc[4][4];
#pragma unroll
  for (int i = 0; i < 4; i++)
#pragma unroll
    for (int j = 0; j < 4; j++)
#pragma unroll
      for (int r = 0; r < 4; r++) acc[i][j][r] = 0.f;

  for (int k0 = 0; k0 < K; k0 += 32) {
    async16(A + a0 + k0, As + tid * 8);
    async16(A + a1 + k0, As + 2048 + tid * 8);
    async16(Bm + b0 + k0, Bs + tid * 8);
    async16(Bm + b1 + k0, Bs + 2048 + tid * 8);
    __syncthreads();   // vmcnt drained by compiler before barrier
    short8 a[4], b[4];
#pragma unroll
    for (int i = 0; i < 4; i++)
      a[i] = *(const short8*)(As + (wm + i * 16 + l16) * 32 + qoff);
#pragma unroll
    for (int j = 0; j < 4; j++)
      b[j] = *(const short8*)(Bs + (wn + j * 16 + l16) * 32 + qoff);
#pragma unroll
    for (int i = 0; i < 4; i++)
#pragma unroll
      for (int j = 0; j < 4; j++)
        acc[i][j] = __builtin_amdgcn_mfma_f32_16x16x32_bf16(a[i], b[j], acc[i][j], 0, 0, 0);
    __syncthreads();   // reads done before next staging
  }
  // C/D layout: col = lane&15, row = quad*4 + reg  [m89/m91 verified]
  const int crow0 = bm + wm + quad * 4;
  const int ccol0 = bn + wn + l16;
#pragma unroll
  for (int i = 0; i < 4; i++)
#pragma unroll
    for (int j = 0; j < 4; j++)
#pragma unroll
      for (int r = 0; r < 4; r++)
        C[(size_t)(crow0 + i * 16 + r) * N + ccol0 + j * 16] = acc[i][j][r];
}

// ---------------- RoPE + staging-layout writes + cache scatter ---------------
// Q staging is pre-scaled by d^-0.5 * log2(e) so attention's S is already in
// the exp2 domain (kills 32 muls per K-tile in the attn inner loop).
__global__ void rope_scatter(
    const float* __restrict__ qkv, const float* __restrict__ cosb,
    const float* __restrict__ sinb, const int* __restrict__ slots,
    unsigned short* __restrict__ qb, unsigned short* __restrict__ kb,
    unsigned short* __restrict__ vb, float* __restrict__ kco,
    float* __restrict__ vco) {
  const float sl2 = 0.08838834764831843f * 1.4426950408889634f;
  const int t = blockIdx.x;
  const int tid = threadIdx.x;
  const int b = t >> 10, s = t & 1023;
  const float* row = qkv + (size_t)t * QKVD;
  const float* cs = cosb + (size_t)t * 64;
  const float* sn = sinb + (size_t)t * 64;
  const int slot = slots[t];
  // Q: rope -> qb (B,H,S,D) bf16, pre-scaled
  for (int wk = tid; wk < H_ * 64; wk += 256) {
    int hh = wk >> 6, i = wk & 63;
    float x1 = row[hh * D_ + i], x2 = row[hh * D_ + 64 + i];
    float c = cs[i], sv = sn[i];
    size_t base = ((size_t)(b * H_ + hh) * S_ + s) * D_;
    qb[base + i]      = f2b((x1 * c - x2 * sv) * sl2);
    qb[base + 64 + i] = f2b((x1 * sv + x2 * c) * sl2);
  }
  // K: rope -> kb (B,KVH,S,D) bf16 + fp32 scatter to cache out
  for (int wk = tid; wk < KVH_ * 64; wk += 256) {
    int hh = wk >> 6, i = wk & 63;
    float x1 = row[H_ * D_ + hh * D_ + i], x2 = row[H_ * D_ + hh * D_ + 64 + i];
    float c = cs[i], sv = sn[i];
    float o1 = x1 * c - x2 * sv, o2 = x1 * sv + x2 * c;
    size_t base = ((size_t)(b * KVH_ + hh) * S_ + s) * D_;
    kb[base + i] = f2b(o1);
    kb[base + 64 + i] = f2b(o2);
    size_t cb = ((size_t)slot * KVH_ + hh) * D_;
    kco[cb + i] = o1;
    kco[cb + 64 + i] = o2;
  }
  // V: copy -> vb (B,KVH,S,D) bf16 + fp32 scatter
  for (int wk = tid; wk < KVH_ * D_; wk += 256) {
    int hh = wk >> 7, i = wk & 127;
    float x = row[H_ * D_ + KVH_ * D_ + hh * D_ + i];
    vb[((size_t)(b * KVH_ + hh) * S_ + s) * D_ + i] = f2b(x);
    vco[((size_t)slot * KVH_ + hh) * D_ + i] = x;
  }
}

// ---------------- V transpose: (BKV,S,D) -> (BKV,D,S) bf16 ----------------
__global__ void transpose_v(const unsigned short* __restrict__ vb,
                            unsigned short* __restrict__ vt) {
  __shared__ unsigned short tile[64][65];
  const int bid = blockIdx.x;
  const int dt = bid & 1, st = (bid >> 1) & 15, bk = bid >> 5;
  const int tid = threadIdx.x;
  const unsigned short* src = vb + ((size_t)bk * S_ + st * 64) * D_ + dt * 64;
#pragma unroll
  for (int k = 0; k < 16; k++) {
    int e = k * 256 + tid, r = e >> 6, c = e & 63;
    tile[r][c] = src[(size_t)r * D_ + c];
  }
  __syncthreads();
  unsigned short* dst = vt + ((size_t)bk * D_ + dt * 64) * S_ + st * 64;
#pragma unroll
  for (int k = 0; k < 16; k++) {
    int e = k * 256 + tid, r = e >> 6, c = e & 63;
    dst[(size_t)r * S_ + c] = tile[c][r];
  }
}

// ---------------- flash attention ----------------
// Block = 4 waves = one (b,h,64-row q-tile). Wave owns 16 q-rows.
// Same 16B-chunk XOR swizzle on all LDS tiles. Row-sum l comes from an extra
// MFMA against a ones-fragment (osum), rescaled by alpha like O -- no sum
// butterfly; l is extracted once in the epilogue with a single shuffle.
// jt==qt (diagonal/masked) iteration is peeled out of the main loop.
__global__ __launch_bounds__(256) void attn_fused(
    const unsigned short* __restrict__ qb, const unsigned short* __restrict__ kb,
    const unsigned short* __restrict__ vt, unsigned short* __restrict__ ob) {
  __shared__ unsigned short Ks[4 * 64 * 32];    // [kc][row][32] 16KB (also Q stage)
  __shared__ unsigned short Vs[2 * 128 * 32];   // [kc][d][32]   16KB
  __shared__ unsigned short Ps[4][2 * 16 * 32]; // per-wave [kc][row][32] 8KB
  const int tid = threadIdx.x;
  const int lane = tid & 63, w = tid >> 6;
  const int quad = lane >> 4, l16 = lane & 15;
  const int bidx = blockIdx.x;
  const int qt = 15 - (bidx & 15);  // heavy q-tiles dispatch first
  const int bh = bidx >> 4;
  const int h = bh & 31, b = bh >> 5;
  const int kvh = h >> 2;
  const int q0 = qt * 64;
  const unsigned short* qbase = qb + ((size_t)bh * S_ + q0) * D_;
  const unsigned short* kbase = kb + (size_t)(b * KVH_ + kvh) * S_ * D_;
  const unsigned short* vbase = vt + (size_t)(b * KVH_ + kvh) * D_ * S_;

  const int srow = tid >> 2;                               // 0..63
  const int scol = (((tid & 3) ^ ((tid >> 3) & 3)) * 8);   // staging swizzle
  const int qoff = (quad ^ ((l16 >> 1) & 3)) * 8;          // frag-read swizzle

  // ---- stage Q into Ks, chunked [kc][row][32] ----
#pragma unroll
  for (int i = 0; i < 4; i++)
    async16(qbase + (size_t)srow * D_ + i * 32 + scol, (unsigned short*)Ks + i * 2048 + tid * 8);
  __syncthreads();
  short8 qf[4];
#pragma unroll
  for (int kc = 0; kc < 4; kc++)
    qf[kc] = *(const short8*)(Ks + (kc * 64 + w * 16 + l16) * 32 + qoff);

  // ones B-fragment: B[n][k]=1 for n==0 (n = l16), else 0
  short8 of;
  {
    unsigned short ov = (l16 == 0) ? (unsigned short)0x3F80 : (unsigned short)0;
#pragma unroll
    for (int j = 0; j < 8; j++) of[j] = (short)ov;
  }

  f32x4 oac[8];
  f32x4 osum;
#pragma unroll
  for (int n = 0; n < 8; n++)
#pragma unroll
    for (int r = 0; r < 4; r++) oac[n][r] = 0.f;
#pragma unroll
  for (int r = 0; r < 4; r++) osum[r] = 0.f;
  float m_run[4] = {-3.0e38f, -3.0e38f, -3.0e38f, -3.0e38f};

  unsigned short* psw = &Ps[w][0];
  const int qrow = q0 + w * 16 + quad * 4;  // + r

  auto body = [&](int jt, bool domask) {
    __syncthreads();  // prior iter LDS reads (and qf reads) complete
    const int j0 = jt * 64;
#pragma unroll
    for (int i = 0; i < 4; i++)
      async16(kbase + (size_t)(j0 + srow) * D_ + i * 32 + scol,
              (unsigned short*)Ks + i * 2048 + tid * 8);
#pragma unroll
    for (int i = 0; i < 4; i++) {
      int kc = i >> 1;
      int d = (i & 1) * 64 + srow;
      async16(vbase + (size_t)d * S_ + j0 + kc * 32 + scol,
              (unsigned short*)Vs + i * 2048 + tid * 8);
    }
    __syncthreads();

    // ---- S = Q K^T (already in exp2 domain; Q pre-scaled) ----
    f32x4 sac[4];
#pragma unroll
    for (int t = 0; t < 4; t++)
#pragma unroll
      for (int r = 0; r < 4; r++) sac[t][r] = 0.f;
#pragma unroll
    for (int t = 0; t < 4; t++)
#pragma unroll
      for (int kc = 0; kc < 4; kc++)
        sac[t] = __builtin_amdgcn_mfma_f32_16x16x32_bf16(
            qf[kc], *(const short8*)(Ks + (kc * 64 + t * 16 + l16) * 32 + qoff),
            sac[t], 0, 0, 0);

    if (domask) {
#pragma unroll
      for (int t = 0; t < 4; t++) {
        const int kcol = j0 + t * 16 + l16;
#pragma unroll
        for (int r = 0; r < 4; r++)
          if (kcol > qrow + r) sac[t][r] = -3.0e38f;
      }
    }
    // ---- row max (16-lane butterfly) ----
    float mx[4];
#pragma unroll
    for (int r = 0; r < 4; r++)
      mx[r] = fmaxf(fmaxf(sac[0][r], sac[1][r]), fmaxf(sac[2][r], sac[3][r]));
#pragma unroll
    for (int off = 1; off < 16; off <<= 1)
#pragma unroll
      for (int r = 0; r < 4; r++) mx[r] = fmaxf(mx[r], __shfl_xor(mx[r], off));
    float alpha[4];
#pragma unroll
    for (int r = 0; r < 4; r++) {
      float mn = fmaxf(m_run[r], mx[r]);
      alpha[r] = exp2f(m_run[r] - mn);
      m_run[r] = mn;
    }
    // ---- P = exp2(S-m) -> LDS (C-layout -> A-layout), swizzled ----
#pragma unroll
    for (int t = 0; t < 4; t++)
#pragma unroll
      for (int r = 0; r < 4; r++) {
        float p = exp2f(sac[t][r] - m_run[r]);
        int prow = quad * 4 + r;
        int chunk = (((t & 1) * 2 + (l16 >> 3)) ^ ((prow >> 1) & 3));
        psw[(t >> 1) * 512 + prow * 32 + chunk * 8 + (l16 & 7)] = f2b(p);
      }
    // ---- rescale accumulators (osum carries the running row-sum l) ----
#pragma unroll
    for (int r = 0; r < 4; r++) osum[r] *= alpha[r];
#pragma unroll
    for (int n = 0; n < 8; n++)
#pragma unroll
      for (int r = 0; r < 4; r++) oac[n][r] *= alpha[r];
    // ---- O += P V ; l += P . 1  (wave-local Ps, lgkmcnt-ordered) ----
#pragma unroll
    for (int kc = 0; kc < 2; kc++) {
      short8 pf = *(const short8*)(psw + kc * 512 + l16 * 32 + qoff);
      osum = __builtin_amdgcn_mfma_f32_16x16x32_bf16(pf, of, osum, 0, 0, 0);
#pragma unroll
      for (int n = 0; n < 8; n++)
        oac[n] = __builtin_amdgcn_mfma_f32_16x16x32_bf16(
            pf, *(const short8*)(Vs + (kc * 128 + n * 16 + l16) * 32 + qoff),
            oac[n], 0, 0, 0);
    }
  };

  for (int jt = 0; jt < qt; jt++) body(jt, false);
  body(qt, true);  // diagonal tile with causal mask

  // ---- epilogue: l lives in col 0 of osum (lane quad*16). normalize. ----
  float inv[4];
#pragma unroll
  for (int r = 0; r < 4; r++) {
    float l = __shfl(osum[r], lane & 48, 64);
    inv[r] = 1.0f / l;
  }
  const size_t trow = (size_t)(b * S_ + q0 + w * 16 + quad * 4);
#pragma unroll
  for (int n = 0; n < 8; n++)
#pragma unroll
    for (int r = 0; r < 4; r++)
      ob[(trow + r) * (size_t)(H_ * D_) + h * D_ + n * 16 + l16] =
          f2b(oac[n][r] * inv[r]);
}

// ---------------- launch ----------------
extern "C" void kernel_launch(void* const* d_in, const int* in_sizes, int n_in,
                              void* d_out, int out_size, void* d_ws, size_t ws_size,
                              hipStream_t stream) {
  const float* hidden = (const float*)d_in[0];
  const float* cosb   = (const float*)d_in[1];
  const float* sinb   = (const float*)d_in[2];
  const float* wqkv   = (const float*)d_in[3];
  const float* wo     = (const float*)d_in[4];
  const float* kc_in  = (const float*)d_in[5];
  const float* vc_in  = (const float*)d_in[6];
  const int*   slots  = (const int*)d_in[7];

  float* out    = (float*)d_out;                       // T*HID
  float* kc_out = out + (size_t)T_ * HID;              // NSLOT*KVH*D
  float* vc_out = kc_out + (size_t)NSLOT * KVH_ * D_;

  // workspace carve-up (~296 MB total)
  char* ws = (char*)d_ws;
  unsigned short* hb    = (unsigned short*)ws; ws += (size_t)T_ * HID * 2;
  unsigned short* wqkvb = (unsigned short*)ws; ws += (size_t)QKVD * HID * 2;
  unsigned short* wob   = (unsigned short*)ws; ws += (size_t)HID * HID * 2;
  float*          qkv   = (float*)ws;          ws += (size_t)T_ * QKVD * 4;
  unsigned short* qb    = (unsigned short*)ws; ws += (size_t)T_ * H_ * D_ * 2;
  unsigned short* kb    = (unsigned short*)ws; ws += (size_t)T_ * KVH_ * D_ * 2;
  unsigned short* vb    = (unsigned short*)ws; ws += (size_t)T_ * KVH_ * D_ * 2;
  unsigned short* vt    = (unsigned short*)ws; ws += (size_t)T_ * KVH_ * D_ * 2;
  unsigned short* ob    = (unsigned short*)ws;

  // cache passthrough (scatter overwrites first T slots)
  const size_t cache_bytes = (size_t)NSLOT * KVH_ * D_ * 4;
  hipMemcpyAsync(kc_out, kc_in, cache_bytes, hipMemcpyDeviceToDevice, stream);
  hipMemcpyAsync(vc_out, vc_in, cache_bytes, hipMemcpyDeviceToDevice, stream);

  conv_bf16<<<(T_ * HID / 4) / 256, 256, 0, stream>>>(hidden, hb, T_ * HID / 4);
  conv_bf16<<<(QKVD * HID / 4) / 256, 256, 0, stream>>>(wqkv, wqkvb, QKVD * HID / 4);
  conv_bf16<<<(HID * HID / 4) / 256, 256, 0, stream>>>(wo, wob, HID * HID / 4);

  dim3 g1(QKVD / 128, T_ / 128);
  gemm_bt<<<g1, 256, 0, stream>>>(hb, wqkvb, qkv, T_, QKVD, HID);

  rope_scatter<<<T_, 256, 0, stream>>>(qkv, cosb, sinb, slots, qb, kb, vb, kc_out, vc_out);

  transpose_v<<<B_ * KVH_ * 16 * 2, 256, 0, stream>>>(vb, vt);

  attn_fused<<<B_ * H_ * (S_ / 64), 256, 0, stream>>>(qb, kb, vt, ob);

  dim3 g2(HID / 128, T_ / 128);
  gemm_bt<<<g2, 256, 0, stream>>>(ob, wob, out, T_, HID, HID);
}

// Round 3
// 986.540 us; speedup vs baseline: 1.1906x; 1.1906x over previous
//
#include <hip/hip_runtime.h>
#include <hip/hip_bf16.h>

// ---------------- problem constants ----------------
#define B_    4
#define S_    1024
#define HID   4096
#define H_    32
#define KVH_  8
#define D_    128
#define T_    (B_ * S_)        // 4096
#define QKVD  (H_ * D_ + 2 * KVH_ * D_)  // 6144
#define NSLOT 8192

typedef __attribute__((ext_vector_type(8))) short short8;   // 8 bf16 = 4 VGPRs
typedef __attribute__((ext_vector_type(4))) float f32x4;

__device__ __forceinline__ unsigned short f2b(float f) {
  union { __hip_bfloat16 h; unsigned short u; } c;
  c.h = __float2bfloat16(f);
  return c.u;
}
__device__ __forceinline__ float b2f(unsigned short u) {
  union { unsigned int i; float f; } c;
  c.i = ((unsigned int)u) << 16;
  return c.f;
}

// async global->LDS 16B. LDS dest must be wave-uniform base + lane*16.
__device__ __forceinline__ void async16(const void* g, void* l) {
  __builtin_amdgcn_global_load_lds(
      (const __attribute__((address_space(1))) unsigned int*)g,
      (__attribute__((address_space(3))) unsigned int*)l,
      16, 0, 0);
}

// ---------------- fp32 -> bf16 convert ----------------
__global__ void conv_bf16(const float* __restrict__ src,
                          unsigned short* __restrict__ dst, int n4) {
  int i = blockIdx.x * 256 + threadIdx.x;
  if (i >= n4) return;
  float4 v = reinterpret_cast<const float4*>(src)[i];
  ushort4 o;
  o.x = f2b(v.x); o.y = f2b(v.y); o.z = f2b(v.z); o.w = f2b(v.w);
  reinterpret_cast<ushort4*>(dst)[i] = o;
}

// ---------------- GEMM: C(M,N) = A(M,K)bf16 * B(N,K)bf16 ^T ------------------
// m97 structure: 128x128 tile, BK=32, 4 waves 2x2, 16x16x32 MFMA, linear raster
// (supercolumn raster REGRESSED: p%8 = XCD = N-tile -> every XCD streams all
// of A through its private L2; FETCH 269->711MB. Reverted.)
// LDS 16B-chunk XOR swizzle: SQ_LDS_BANK_CONFLICT == 0 (verified round 2).
template <bool BF16OUT>
__global__ __launch_bounds__(256) void gemm_bt(
    const unsigned short* __restrict__ A, const unsigned short* __restrict__ Bm,
    void* __restrict__ Cv, int M, int N, int K) {
  __shared__ unsigned short As[128 * 32];  // [row][32] swizzled, 8KB
  __shared__ unsigned short Bs[128 * 32];
  const int tid  = threadIdx.x;
  const int lane = tid & 63;
  const int w    = tid >> 6;
  const int quad = lane >> 4;
  const int l16  = lane & 15;
  const int bm = blockIdx.y * 128;
  const int bn = blockIdx.x * 128;
  const int wm = (w >> 1) * 64;
  const int wn = (w & 1) * 64;

  const int srow = tid >> 2;                               // 0..63
  const int scol = (((tid & 3) ^ ((tid >> 3) & 3)) * 8);   // swizzled src chunk
  const int qoff = (quad ^ ((l16 >> 1) & 3)) * 8;          // swizzled frag chunk

  // running global staging pointers (pointer-bump, minimal in-loop VALU)
  const unsigned short* gA0 = A + (size_t)(bm + srow) * K + scol;
  const unsigned short* gA1 = A + (size_t)(bm + 64 + srow) * K + scol;
  const unsigned short* gB0 = Bm + (size_t)(bn + srow) * K + scol;
  const unsigned short* gB1 = Bm + (size_t)(bn + 64 + srow) * K + scol;
  unsigned short* lA0 = As + tid * 8;
  unsigned short* lA1 = As + 2048 + tid * 8;
  unsigned short* lB0 = Bs + tid * 8;
  unsigned short* lB1 = Bs + 2048 + tid * 8;

  // hoisted LDS fragment pointers (loop-invariant)
  const unsigned short* pa[4];
  const unsigned short* pb[4];
#pragma unroll
  for (int i = 0; i < 4; i++) {
    pa[i] = As + (wm + i * 16 + l16) * 32 + qoff;
    pb[i] = Bs + (wn + i * 16 + l16) * 32 + qoff;
  }

  f32x4 acc[4][4];
#pragma unroll
  for (int i = 0; i < 4; i++)
#pragma unroll
    for (int j = 0; j < 4; j++)
#pragma unroll
      for (int r = 0; r < 4; r++) acc[i][j][r] = 0.f;

  for (int k0 = 0; k0 < K; k0 += 32) {
    async16(gA0, lA0);
    async16(gA1, lA1);
    async16(gB0, lB0);
    async16(gB1, lB1);
    gA0 += 32; gA1 += 32; gB0 += 32; gB1 += 32;
    __syncthreads();   // vmcnt drained by compiler before barrier
    short8 a[4], b[4];
#pragma unroll
    for (int i = 0; i < 4; i++) a[i] = *(const short8*)pa[i];
#pragma unroll
    for (int j = 0; j < 4; j++) b[j] = *(const short8*)pb[j];
#pragma unroll
    for (int i = 0; i < 4; i++)
#pragma unroll
      for (int j = 0; j < 4; j++)
        acc[i][j] = __builtin_amdgcn_mfma_f32_16x16x32_bf16(a[i], b[j], acc[i][j], 0, 0, 0);
    __syncthreads();   // reads done before next staging
  }
  // C/D layout: col = lane&15, row = quad*4 + reg  [m89/m91 verified]
  const int crow0 = bm + wm + quad * 4;
  const int ccol0 = bn + wn + l16;
  if constexpr (BF16OUT) {
    unsigned short* C = (unsigned short*)Cv;
#pragma unroll
    for (int i = 0; i < 4; i++)
#pragma unroll
      for (int j = 0; j < 4; j++)
#pragma unroll
        for (int r = 0; r < 4; r++)
          C[(size_t)(crow0 + i * 16 + r) * N + ccol0 + j * 16] = f2b(acc[i][j][r]);
  } else {
    float* C = (float*)Cv;
#pragma unroll
    for (int i = 0; i < 4; i++)
#pragma unroll
      for (int j = 0; j < 4; j++)
#pragma unroll
        for (int r = 0; r < 4; r++)
          C[(size_t)(crow0 + i * 16 + r) * N + ccol0 + j * 16] = acc[i][j][r];
  }
}

// ---------------- RoPE + staging-layout writes + cache scatter ---------------
// qkv arrives as bf16 (GEMM writes bf16 directly: halves qkv traffic).
// Q staging is pre-scaled by d^-0.5 * log2(e) so attention's S is already in
// the exp2 domain.
__global__ void rope_scatter(
    const unsigned short* __restrict__ qkv, const float* __restrict__ cosb,
    const float* __restrict__ sinb, const int* __restrict__ slots,
    unsigned short* __restrict__ qb, unsigned short* __restrict__ kb,
    unsigned short* __restrict__ vb, float* __restrict__ kco,
    float* __restrict__ vco) {
  const float sl2 = 0.08838834764831843f * 1.4426950408889634f;
  const int t = blockIdx.x;
  const int tid = threadIdx.x;
  const int b = t >> 10, s = t & 1023;
  const unsigned short* row = qkv + (size_t)t * QKVD;
  const float* cs = cosb + (size_t)t * 64;
  const float* sn = sinb + (size_t)t * 64;
  const int slot = slots[t];
  // Q: rope -> qb (B,H,S,D) bf16, pre-scaled
  for (int wk = tid; wk < H_ * 64; wk += 256) {
    int hh = wk >> 6, i = wk & 63;
    float x1 = b2f(row[hh * D_ + i]), x2 = b2f(row[hh * D_ + 64 + i]);
    float c = cs[i], sv = sn[i];
    size_t base = ((size_t)(b * H_ + hh) * S_ + s) * D_;
    qb[base + i]      = f2b((x1 * c - x2 * sv) * sl2);
    qb[base + 64 + i] = f2b((x1 * sv + x2 * c) * sl2);
  }
  // K: rope -> kb (B,KVH,S,D) bf16 + fp32 scatter to cache out
  for (int wk = tid; wk < KVH_ * 64; wk += 256) {
    int hh = wk >> 6, i = wk & 63;
    float x1 = b2f(row[H_ * D_ + hh * D_ + i]);
    float x2 = b2f(row[H_ * D_ + hh * D_ + 64 + i]);
    float c = cs[i], sv = sn[i];
    float o1 = x1 * c - x2 * sv, o2 = x1 * sv + x2 * c;
    size_t base = ((size_t)(b * KVH_ + hh) * S_ + s) * D_;
    kb[base + i] = f2b(o1);
    kb[base + 64 + i] = f2b(o2);
    size_t cb = ((size_t)slot * KVH_ + hh) * D_;
    kco[cb + i] = o1;
    kco[cb + 64 + i] = o2;
  }
  // V: copy -> vb (B,KVH,S,D) bf16 + fp32 scatter
  for (int wk = tid; wk < KVH_ * D_; wk += 256) {
    int hh = wk >> 7, i = wk & 127;
    unsigned short xv = row[H_ * D_ + KVH_ * D_ + hh * D_ + i];
    vb[((size_t)(b * KVH_ + hh) * S_ + s) * D_ + i] = xv;
    vco[((size_t)slot * KVH_ + hh) * D_ + i] = b2f(xv);
  }
}

// ---------------- V transpose: (BKV,S,D) -> (BKV,D,S) bf16 ----------------
__global__ void transpose_v(const unsigned short* __restrict__ vb,
                            unsigned short* __restrict__ vt) {
  __shared__ unsigned short tile[64][65];
  const int bid = blockIdx.x;
  const int dt = bid & 1, st = (bid >> 1) & 15, bk = bid >> 5;
  const int tid = threadIdx.x;
  const unsigned short* src = vb + ((size_t)bk * S_ + st * 64) * D_ + dt * 64;
#pragma unroll
  for (int k = 0; k < 16; k++) {
    int e = k * 256 + tid, r = e >> 6, c = e & 63;
    tile[r][c] = src[(size_t)r * D_ + c];
  }
  __syncthreads();
  unsigned short* dst = vt + ((size_t)bk * D_ + dt * 64) * S_ + st * 64;
#pragma unroll
  for (int k = 0; k < 16; k++) {
    int e = k * 256 + tid, r = e >> 6, c = e & 63;
    dst[(size_t)r * S_ + c] = tile[c][r];
  }
}

// ---------------- flash attention ----------------
// Block = 4 waves = one (b,h,64-row q-tile). Wave owns 16 q-rows.
// Row-sum l via MFMA against a ones-fragment (osum); diagonal mask is a
// scalar-guarded branch inside the single loop (no lambda / peel).
__global__ __launch_bounds__(256) void attn_fused(
    const unsigned short* __restrict__ qb, const unsigned short* __restrict__ kb,
    const unsigned short* __restrict__ vt, unsigned short* __restrict__ ob) {
  __shared__ unsigned short Ks[4 * 64 * 32];    // [kc][row][32] 16KB (also Q stage)
  __shared__ unsigned short Vs[2 * 128 * 32];   // [kc][d][32]   16KB
  __shared__ unsigned short Ps[4][2 * 16 * 32]; // per-wave [kc][row][32] 8KB
  const int tid = threadIdx.x;
  const int lane = tid & 63, w = tid >> 6;
  const int quad = lane >> 4, l16 = lane & 15;
  const int bidx = blockIdx.x;
  const int qt = 15 - (bidx & 15);  // heavy q-tiles dispatch first
  const int bh = bidx >> 4;
  const int h = bh & 31, b = bh >> 5;
  const int kvh = h >> 2;
  const int q0 = qt * 64;
  const unsigned short* qbase = qb + ((size_t)bh * S_ + q0) * D_;
  const unsigned short* kbase = kb + (size_t)(b * KVH_ + kvh) * S_ * D_;
  const unsigned short* vbase = vt + (size_t)(b * KVH_ + kvh) * D_ * S_;

  const int srow = tid >> 2;                               // 0..63
  const int scol = (((tid & 3) ^ ((tid >> 3) & 3)) * 8);   // staging swizzle
  const int qoff = (quad ^ ((l16 >> 1) & 3)) * 8;          // frag-read swizzle

  // ---- stage Q into Ks, chunked [kc][row][32] ----
#pragma unroll
  for (int i = 0; i < 4; i++)
    async16(qbase + (size_t)srow * D_ + i * 32 + scol, (unsigned short*)Ks + i * 2048 + tid * 8);
  __syncthreads();
  short8 qf[4];
#pragma unroll
  for (int kc = 0; kc < 4; kc++)
    qf[kc] = *(const short8*)(Ks + (kc * 64 + w * 16 + l16) * 32 + qoff);

  // ones B-fragment: B[n][k]=1 for n==0 (n = l16), else 0
  short8 of;
  {
    unsigned short ov = (l16 == 0) ? (unsigned short)0x3F80 : (unsigned short)0;
#pragma unroll
    for (int j = 0; j < 8; j++) of[j] = (short)ov;
  }

  f32x4 oac[8];
  f32x4 osum;
#pragma unroll
  for (int n = 0; n < 8; n++)
#pragma unroll
    for (int r = 0; r < 4; r++) oac[n][r] = 0.f;
#pragma unroll
  for (int r = 0; r < 4; r++) osum[r] = 0.f;
  float m_run[4] = {-3.0e38f, -3.0e38f, -3.0e38f, -3.0e38f};

  unsigned short* psw = &Ps[w][0];
  const int qrow = q0 + w * 16 + quad * 4;  // + r

  for (int jt = 0; jt <= qt; jt++) {
    __syncthreads();  // prior iter LDS reads (and qf reads) complete
    const int j0 = jt * 64;
#pragma unroll
    for (int i = 0; i < 4; i++)
      async16(kbase + (size_t)(j0 + srow) * D_ + i * 32 + scol,
              (unsigned short*)Ks + i * 2048 + tid * 8);
#pragma unroll
    for (int i = 0; i < 4; i++) {
      int kc = i >> 1;
      int d = (i & 1) * 64 + srow;
      async16(vbase + (size_t)d * S_ + j0 + kc * 32 + scol,
              (unsigned short*)Vs + i * 2048 + tid * 8);
    }
    __syncthreads();

    // ---- S = Q K^T (already in exp2 domain; Q pre-scaled) ----
    f32x4 sac[4];
#pragma unroll
    for (int t = 0; t < 4; t++)
#pragma unroll
      for (int r = 0; r < 4; r++) sac[t][r] = 0.f;
#pragma unroll
    for (int t = 0; t < 4; t++)
#pragma unroll
      for (int kc = 0; kc < 4; kc++)
        sac[t] = __builtin_amdgcn_mfma_f32_16x16x32_bf16(
            qf[kc], *(const short8*)(Ks + (kc * 64 + t * 16 + l16) * 32 + qoff),
            sac[t], 0, 0, 0);

    if (jt == qt) {  // scalar-uniform branch: diagonal tile causal mask
#pragma unroll
      for (int t = 0; t < 4; t++) {
        const int kcol = j0 + t * 16 + l16;
#pragma unroll
        for (int r = 0; r < 4; r++)
          if (kcol > qrow + r) sac[t][r] = -3.0e38f;
      }
    }
    // ---- row max (16-lane butterfly) ----
    float mx[4];
#pragma unroll
    for (int r = 0; r < 4; r++)
      mx[r] = fmaxf(fmaxf(sac[0][r], sac[1][r]), fmaxf(sac[2][r], sac[3][r]));
#pragma unroll
    for (int off = 1; off < 16; off <<= 1)
#pragma unroll
      for (int r = 0; r < 4; r++) mx[r] = fmaxf(mx[r], __shfl_xor(mx[r], off));
    float alpha[4];
#pragma unroll
    for (int r = 0; r < 4; r++) {
      float mn = fmaxf(m_run[r], mx[r]);
      alpha[r] = exp2f(m_run[r] - mn);
      m_run[r] = mn;
    }
    // ---- P = exp2(S-m) -> LDS (C-layout -> A-layout), swizzled ----
#pragma unroll
    for (int t = 0; t < 4; t++)
#pragma unroll
      for (int r = 0; r < 4; r++) {
        float p = exp2f(sac[t][r] - m_run[r]);
        int prow = quad * 4 + r;
        int chunk = (((t & 1) * 2 + (l16 >> 3)) ^ ((prow >> 1) & 3));
        psw[(t >> 1) * 512 + prow * 32 + chunk * 8 + (l16 & 7)] = f2b(p);
      }
    // ---- rescale accumulators (osum carries the running row-sum l) ----
#pragma unroll
    for (int r = 0; r < 4; r++) osum[r] *= alpha[r];
#pragma unroll
    for (int n = 0; n < 8; n++)
#pragma unroll
      for (int r = 0; r < 4; r++) oac[n][r] *= alpha[r];
    // ---- O += P V ; l += P . 1  (wave-local Ps, lgkmcnt-ordered) ----
#pragma unroll
    for (int kc = 0; kc < 2; kc++) {
      short8 pf = *(const short8*)(psw + kc * 512 + l16 * 32 + qoff);
      osum = __builtin_amdgcn_mfma_f32_16x16x32_bf16(pf, of, osum, 0, 0, 0);
#pragma unroll
      for (int n = 0; n < 8; n++)
        oac[n] = __builtin_amdgcn_mfma_f32_16x16x32_bf16(
            pf, *(const short8*)(Vs + (kc * 128 + n * 16 + l16) * 32 + qoff),
            oac[n], 0, 0, 0);
    }
  }

  // ---- epilogue: l lives in col 0 of osum (lane quad*16). normalize. ----
  float inv[4];
#pragma unroll
  for (int r = 0; r < 4; r++) {
    float l = __shfl(osum[r], lane & 48, 64);
    inv[r] = 1.0f / l;
  }
  const size_t trow = (size_t)(b * S_ + q0 + w * 16 + quad * 4);
#pragma unroll
  for (int n = 0; n < 8; n++)
#pragma unroll
    for (int r = 0; r < 4; r++)
      ob[(trow + r) * (size_t)(H_ * D_) + h * D_ + n * 16 + l16] =
          f2b(oac[n][r] * inv[r]);
}

// ---------------- launch ----------------
extern "C" void kernel_launch(void* const* d_in, const int* in_sizes, int n_in,
                              void* d_out, int out_size, void* d_ws, size_t ws_size,
                              hipStream_t stream) {
  const float* hidden = (const float*)d_in[0];
  const float* cosb   = (const float*)d_in[1];
  const float* sinb   = (const float*)d_in[2];
  const float* wqkv   = (const float*)d_in[3];
  const float* wo     = (const float*)d_in[4];
  const float* kc_in  = (const float*)d_in[5];
  const float* vc_in  = (const float*)d_in[6];
  const int*   slots  = (const int*)d_in[7];

  float* out    = (float*)d_out;                       // T*HID
  float* kc_out = out + (size_t)T_ * HID;              // NSLOT*KVH*D
  float* vc_out = kc_out + (size_t)NSLOT * KVH_ * D_;

  // workspace carve-up
  char* ws = (char*)d_ws;
  unsigned short* hb    = (unsigned short*)ws; ws += (size_t)T_ * HID * 2;
  unsigned short* wqkvb = (unsigned short*)ws; ws += (size_t)QKVD * HID * 2;
  unsigned short* wob   = (unsigned short*)ws; ws += (size_t)HID * HID * 2;
  unsigned short* qkv   = (unsigned short*)ws; ws += (size_t)T_ * QKVD * 2;
  unsigned short* qb    = (unsigned short*)ws; ws += (size_t)T_ * H_ * D_ * 2;
  unsigned short* kb    = (unsigned short*)ws; ws += (size_t)T_ * KVH_ * D_ * 2;
  unsigned short* vb    = (unsigned short*)ws; ws += (size_t)T_ * KVH_ * D_ * 2;
  unsigned short* vt    = (unsigned short*)ws; ws += (size_t)T_ * KVH_ * D_ * 2;
  unsigned short* ob    = (unsigned short*)ws;

  // cache passthrough (scatter overwrites first T slots)
  const size_t cache_bytes = (size_t)NSLOT * KVH_ * D_ * 4;
  hipMemcpyAsync(kc_out, kc_in, cache_bytes, hipMemcpyDeviceToDevice, stream);
  hipMemcpyAsync(vc_out, vc_in, cache_bytes, hipMemcpyDeviceToDevice, stream);

  conv_bf16<<<(T_ * HID / 4) / 256, 256, 0, stream>>>(hidden, hb, T_ * HID / 4);
  conv_bf16<<<(QKVD * HID / 4) / 256, 256, 0, stream>>>(wqkv, wqkvb, QKVD * HID / 4);
  conv_bf16<<<(HID * HID / 4) / 256, 256, 0, stream>>>(wo, wob, HID * HID / 4);

  dim3 g1(QKVD / 128, T_ / 128);
  gemm_bt<true><<<g1, 256, 0, stream>>>(hb, wqkvb, qkv, T_, QKVD, HID);

  rope_scatter<<<T_, 256, 0, stream>>>(qkv, cosb, sinb, slots, qb, kb, vb, kc_out, vc_out);

  transpose_v<<<B_ * KVH_ * 16 * 2, 256, 0, stream>>>(vb, vt);

  attn_fused<<<B_ * H_ * (S_ / 64), 256, 0, stream>>>(qb, kb, vt, ob);

  dim3 g2(HID / 128, T_ / 128);
  gemm_bt<false><<<g2, 256, 0, stream>>>(ob, wob, out, T_, HID, HID);
}